// Round 6
// baseline (204.836 us; speedup 1.0000x reference)
//
#include <hip/hip_runtime.h>

#define T_LEN 131072
#define KDIM 128
#define CHUNK 16
#define WARM 16
#define NSTEP (CHUNK + WARM)       // 32
#define NCHUNK (T_LEN / CHUNK)     // 8192
#define GROUPC 16                  // chunks per cluster = MFMA M
#define CLUST 2                    // clusters per block
#define NBLK (NCHUNK / (GROUPC * CLUST))   // 256 blocks, 1/CU
#define NGRP2 (NCHUNK / GROUPC)            // 512 groups
#define CSHIFT 4.5f

typedef float v4f __attribute__((ext_vector_type(4)));
typedef short s8v __attribute__((ext_vector_type(8)));   // 8 bf16 (4 VGPRs)

__device__ __forceinline__ int trans_idx(int w2w, int ic, int dist) {
    return (w2w == 1) ? 0 : (ic == 0 ? 1 : (dist == 0 ? 2 : 3));
}
// f32 -> bf16, RNE (not RTZ: half-ulp bias accumulates over 131k steps)
__device__ __forceinline__ unsigned short bf16rne(float x) {
    unsigned u = __float_as_uint(x);
    return (unsigned short)((u + 0x7fffu + ((u >> 16) & 1u)) >> 16);
}
__device__ __forceinline__ float bf16tof(unsigned short h) {
    return __uint_as_float(((unsigned)h) << 16);
}

// ---- MFMA CRF scan, v3: two independent 16-chunk clusters in ONE 512-thread
// workgroup -> 8 waves = 2 waves/SIMD guaranteed co-resident (round 5's
// 2-blocks/CU never materialized: occupancy stayed 10.6%). Cluster cl owns its
// own A-tile dbuf + bookkeeping; E-fragments (identical for all) built once.
// __launch_bounds__(512) => 1 WG/CU floor => VGPR cap 256 > ~184 working set,
// so no spill (round-4 trap). Math identical to verified rounds 4/5.
__global__ void __launch_bounds__(512) scan_kernel(
    const float* __restrict__ em, const float* __restrict__ trans,
    const float* __restrict__ start, const float* __restrict__ cw,
    const int* __restrict__ tags, const int* __restrict__ w2w,
    const int* __restrict__ ic, const int* __restrict__ dist,
    double* __restrict__ goldslots, double* __restrict__ logzslots,
    unsigned* __restrict__ donecnt, float* __restrict__ out)
{
    const int tid = threadIdx.x;
    const int wv  = tid >> 6;        // 0..7
    const int cl  = wv >> 2;         // cluster 0/1
    const int wvc = wv & 3;          // wave-in-cluster -> N-cols 32wvc..
    const int ln  = tid & 63;
    const int lr  = ln & 15;         // A-row / B-col lane id
    const int hq  = ln >> 4;         // 0..3: k-slab and C/D row-quad
    const int grp2 = (blockIdx.x << 1) | cl;    // group id 0..511

    __shared__ float SS[32][130];                                  // 16.6 KB stage tile
    __shared__ __align__(16) unsigned short A[CLUST][2][GROUPC * KDIM]; // 16 KB
    __shared__ double bg[8];
    __shared__ double bzred[CLUST];
    __shared__ double redd[256];
    __shared__ int islast;

    // ---- stage E: 16 passes (m,ks); coalesced loads + LDS transpose ----
    // 512 threads: each loads 8 floats/pass (one 32x128 slab per pass).
    s8v Bf[4][2][4];
    const int ncol = (wvc << 5) + lr;
    {
        const int sr = tid >> 4;              // LDS row 0..31
        const int sc = (tid & 15) << 3;       // LDS col 0..120
        float4 nx0, nx1;
        {
            const float* s = trans + (tid << 3);
            nx0 = *(const float4*)(s); nx1 = *(const float4*)(s + 4);
        }
        #pragma unroll
        for (int p = 0; p < 16; ++p) {        // p = m*4 + ks; src off = p<<12
            const int m = p >> 2, ks = p & 3;
            ((float2*)&SS[sr][sc])[0] = make_float2(nx0.x, nx0.y);
            ((float2*)&SS[sr][sc])[1] = make_float2(nx0.z, nx0.w);
            ((float2*)&SS[sr][sc + 4])[0] = make_float2(nx1.x, nx1.y);
            ((float2*)&SS[sr][sc + 4])[1] = make_float2(nx1.z, nx1.w);
            __syncthreads();
            if (p < 15) {                     // prefetch next pass under reads
                const float* s = trans + ((p + 1) << 12) + (tid << 3);
                nx0 = *(const float4*)(s); nx1 = *(const float4*)(s + 4);
            }
            s8v f0, f1;
            #pragma unroll
            for (int j = 0; j < 8; ++j) {
                f0[j] = (short)bf16rne(__expf(SS[(hq << 3) + j][ncol]));
                f1[j] = (short)bf16rne(__expf(SS[(hq << 3) + j][ncol + 16]));
            }
            Bf[m][0][ks] = f0;
            Bf[m][1][ks] = f1;
            __syncthreads();
        }
    }

    // ---- gold: block covers 512 t's, 1 per thread ----
    {
        float gp = 0.f;
        const int t = 1 + (blockIdx.x << 9) + tid;
        if (t < T_LEN) {
            const int tg  = tags[t];
            const int tgp = tags[t - 1];
            const int mm  = trans_idx(w2w[t - 1], ic[t - 1], dist[t - 1]);
            gp = cw[tg] * (trans[((size_t)mm * KDIM + tgp) * KDIM + tg] +
                           em[(size_t)t * KDIM + tg]);
        }
        if (blockIdx.x == 0 && tid == 0) {
            const int tg0 = tags[0];
            gp += cw[tg0] * (start[tg0] + em[tg0]);
        }
        float r = gp;
        #pragma unroll
        for (int off = 32; off; off >>= 1) r += __shfl_down(r, off, 64);
        if (ln == 0) bg[wv] = (double)r;
    }

    // ---- init A tile (wave wvc==0 of each cluster) ----
    if (wvc == 0) {
        const int c_row = (grp2 << 4) + lr;
        #pragma unroll
        for (int kk = 0; kk < 32; kk += 2) {
            const int k = (hq << 5) + kk;
            float a0, a1;
            if (c_row == 0) {
                a0 = __expf(start[k] + em[k]);
                a1 = __expf(start[k + 1] + em[k + 1]);
            } else { a0 = 1.f; a1 = 1.f; }
            const int off = (lr << 8) + ((k << 1) ^ ((lr & 7) << 4));
            *(unsigned*)((char*)A[cl][0] + off) =
                (unsigned)bf16rne(a0) | ((unsigned)bf16rne(a1) << 16);
        }
    }
    __syncthreads();

    // ---- per-row bookkeeping ----
    int t0r[4];
    #pragma unroll
    for (int r = 0; r < 4; ++r) {
        const int c_r = (grp2 << 4) + (hq << 2) + r;
        t0r[r] = (c_r == 0) ? 1 : (1 + c_r * CHUNK - WARM);
    }
    const int c_lr   = (grp2 << 4) + lr;    // row this lane tracks s/g for
    const int town_l = 1 + c_lr * CHUNK;
    const int tend_l = min(town_l + CHUNK, T_LEN);
    const int t0_l   = (c_lr == 0) ? 1 : (town_l - WARM);

    int pmw, pmi, pmd;
    {
        const int ix = min(t0_l - 1, T_LEN - 2);
        pmw = w2w[ix]; pmi = ic[ix]; pmd = dist[ix];
    }
    float pem[2][4];
    #pragma unroll
    for (int r = 0; r < 4; ++r) {
        const int t = min(t0r[r], T_LEN - 1);
        pem[0][r] = em[(size_t)t * KDIM + ncol];
        pem[1][r] = em[(size_t)t * KDIM + ncol + 16];
    }

    float g = 0.f;
    float sc4[4] = {1.f, 1.f, 1.f, 1.f};

    for (int it = 0; it <= NSTEP; ++it) {
        // (1) read A fragments (v after step t-1), swizzled
        s8v Af[4];
        #pragma unroll
        for (int ks = 0; ks < 4; ++ks) {
            const int off = (lr << 8) + (((ks << 6) + (hq << 4)) ^ ((lr & 7) << 4));
            Af[ks] = *(const s8v*)((const char*)A[cl][it & 1] + off);
        }

        // (2) renorm bookkeeping on v(t-1): same events as rounds 3-5
        const bool trig = ((it & 7) == 0) || (grp2 == NGRP2 - 1 && it == NSTEP - 1);
        if (trig) {
            float s = 0.f;
            #pragma unroll
            for (int ks = 0; ks < 4; ++ks) {
                #pragma unroll
                for (int j = 0; j < 8; ++j)
                    s += bf16tof((unsigned short)Af[ks][j]);
            }
            s += __shfl_xor(s, 16, 64);
            s += __shfl_xor(s, 32, 64);       // full row-sum for row lr
            const int tprev = t0_l + it - 1;
            const bool dn = ((tprev & 7) == 0) || (tprev == T_LEN - 1);
            const float scl = dn ? (1.f / s) : 1.f;
            if (it == 0) {
                if (c_lr == 0) g += __logf(s);        // base measure log s0
            } else if (dn && tprev >= town_l && tprev < tend_l) {
                g += __logf(s);
            }
            #pragma unroll
            for (int r = 0; r < 4; ++r) sc4[r] = __shfl(scl, (hq << 2) + r, 64);
        }
        if (it == NSTEP) break;

        // (3) per-row transition index + emission factors
        const int mcur = trans_idx(pmw, pmi, pmd);
        int m4[4];
        #pragma unroll
        for (int r = 0; r < 4; ++r) m4[r] = __shfl(mcur, (hq << 2) + r, 64);
        float dv[2][4];
        #pragma unroll
        for (int nt = 0; nt < 2; ++nt) {
            #pragma unroll
            for (int r = 0; r < 4; ++r)
                dv[nt][r] = __expf(pem[nt][r] - CSHIFT) * sc4[r];
        }

        // (4) prefetch next step (issued before MFMA so latency hides)
        {
            const int ix = min(t0_l + it, T_LEN - 2);
            pmw = w2w[ix]; pmi = ic[ix]; pmd = dist[ix];
        }
        #pragma unroll
        for (int r = 0; r < 4; ++r) {
            const int t = min(t0r[r] + it + 1, T_LEN - 1);
            pem[0][r] = em[(size_t)t * KDIM + ncol];
            pem[1][r] = em[(size_t)t * KDIM + ncol + 16];
        }

        // (5) 32 MFMAs: all 4 m, 2 N-tiles, K=128
        v4f acc[4][2];
        #pragma unroll
        for (int m = 0; m < 4; ++m) {
            #pragma unroll
            for (int nt = 0; nt < 2; ++nt) acc[m][nt] = (v4f)0.f;
        }
        #pragma unroll
        for (int ks = 0; ks < 4; ++ks) {
            #pragma unroll
            for (int m = 0; m < 4; ++m) {
                #pragma unroll
                for (int nt = 0; nt < 2; ++nt)
                    acc[m][nt] = __builtin_amdgcn_mfma_f32_16x16x32_bf16(
                        Af[ks], Bf[m][nt][ks], acc[m][nt], 0, 0, 0);
            }
        }

        // (6) select m per row, apply emission*scale, write next A tile (bf16)
        #pragma unroll
        for (int nt = 0; nt < 2; ++nt) {
            #pragma unroll
            for (int r = 0; r < 4; ++r) {
                const int mm = m4[r];
                float y = acc[0][nt][r];
                y = (mm == 1) ? acc[1][nt][r] : y;
                y = (mm == 2) ? acc[2][nt][r] : y;
                y = (mm == 3) ? acc[3][nt][r] : y;
                y *= dv[nt][r];
                const int row = (hq << 2) + r;
                const int col = (wvc << 5) + (nt << 4) + lr;
                const int off = (row << 8) + ((col << 1) ^ ((row & 7) << 4));
                *(unsigned short*)((char*)A[cl][(it & 1) ^ 1] + off) = bf16rne(y);
            }
        }
        #pragma unroll
        for (int r = 0; r < 4; ++r) sc4[r] = 1.f;
        __syncthreads();
    }

    // ---- logZ reduce: lanes<16 of wave wvc==0 hold g for cluster rows 0..15 ----
    if (wvc == 0) {
        float gz = (ln < 16) ? (g + CSHIFT * (float)(tend_l - town_l)) : 0.f;
        float r = gz;
        #pragma unroll
        for (int off = 32; off; off >>= 1) r += __shfl_down(r, off, 64);
        if (ln == 0) bzred[cl] = (double)r;
    }
    __syncthreads();

    // ---- publish slots (tid0 only, so its fence covers them); last block reduces ----
    if (tid == 0) {
        goldslots[blockIdx.x] = bg[0] + bg[1] + bg[2] + bg[3] +
                                bg[4] + bg[5] + bg[6] + bg[7];
        logzslots[(blockIdx.x << 1) | 0] = bzred[0];
        logzslots[(blockIdx.x << 1) | 1] = bzred[1];
        __threadfence();
        const unsigned prev = atomicAdd(donecnt, 1u);
        islast = (prev == NBLK - 1) ? 1 : 0;
    }
    __syncthreads();
    if (islast) {
        __threadfence();
        if (tid < 256) redd[tid] = goldslots[tid];
        __syncthreads();
        for (int s = 128; s > 0; s >>= 1) {
            if (tid < s) redd[tid] += redd[tid + s];
            __syncthreads();
        }
        if (tid == 0) out[0] = (float)redd[0];
        __syncthreads();
        if (tid < 256) redd[tid] = logzslots[tid] + logzslots[tid + 256];
        __syncthreads();
        for (int s = 128; s > 0; s >>= 1) {
            if (tid < s) redd[tid] += redd[tid + s];
            __syncthreads();
        }
        if (tid == 0) out[1] = (float)redd[0];
    }
}

extern "C" void kernel_launch(void* const* d_in, const int* in_sizes, int n_in,
                              void* d_out, int out_size, void* d_ws, size_t ws_size,
                              hipStream_t stream) {
    const float* emissions = (const float*)d_in[0];
    const float* trans     = (const float*)d_in[1];
    const float* start     = (const float*)d_in[2];
    const float* cw        = (const float*)d_in[3];
    const int*   tags      = (const int*)d_in[4];
    const int*   w2w       = (const int*)d_in[5];
    const int*   icnt      = (const int*)d_in[6];
    const int*   dist      = (const int*)d_in[7];

    double*   goldslots = (double*)d_ws;            // NBLK doubles (256)
    double*   logzslots = (double*)d_ws + 512;      // NGRP2 doubles (512)
    unsigned* donecnt   = (unsigned*)((double*)d_ws + 1024);

    hipMemsetAsync(donecnt, 0, sizeof(unsigned), stream);
    scan_kernel<<<NBLK, 512, 0, stream>>>(emissions, trans, start, cw, tags,
                                          w2w, icnt, dist, goldslots, logzslots,
                                          donecnt, (float*)d_out);
}

// Round 7
// 170.736 us; speedup vs baseline: 1.1997x; 1.1997x over previous
//
#include <hip/hip_runtime.h>

#define T_LEN 131072
#define KDIM 128
#define CHUNK 32
#define WARM 16
#define NSTEP (CHUNK + WARM)       // 48
#define NCHUNK (T_LEN / CHUNK)     // 4096
#define GROUPC 16                  // chunks per group = MFMA M
#define NGRP (NCHUNK / GROUPC)     // 256 blocks, 1/CU
#define CSHIFT 4.5f

typedef float v4f __attribute__((ext_vector_type(4)));
typedef short s8v __attribute__((ext_vector_type(8)));   // 8 bf16 (4 VGPRs)

__device__ __forceinline__ int trans_idx(int w2w, int ic, int dist) {
    return (w2w == 1) ? 0 : (ic == 0 ? 1 : (dist == 0 ? 2 : 3));
}
// f32 -> bf16, RNE (not RTZ: half-ulp bias accumulates over 131k steps)
__device__ __forceinline__ unsigned short bf16rne(float x) {
    unsigned u = __float_as_uint(x);
    return (unsigned short)((u + 0x7fffu + ((u >> 16) & 1u)) >> 16);
}
__device__ __forceinline__ float bf16tof(unsigned short h) {
    return __uint_as_float(((unsigned)h) << 16);
}

// ---- MFMA CRF scan, v4: m-SPLIT wave pairs ----
// Round-3 geometry (CHUNK 32, 16-chunk group, 256 blocks) but 8 waves/block:
// wave = (mh, wvc); wvc = column range 32wvc..32wvc+31, mh = which half of the
// 4 transition matrices this wave holds (m in {2mh, 2mh+1}).  Bf drops from
// 128 -> 64 VGPRs, so total ~150 regs: 2 waves/SIMD co-resident WITHOUT a
// register cap below the working set (rounds 4/6 spilled at cap 128).
// Each wave runs its 2 m-MFMAs and writes only rows whose selected m is in
// its half -- rows partition across the pair, union is the full A-tile.
// Math/renorm events identical to verified rounds 3-6 lineage.
__global__ void __launch_bounds__(512, 1) scan_kernel(
    const float* __restrict__ em, const float* __restrict__ trans,
    const float* __restrict__ start, const float* __restrict__ cw,
    const int* __restrict__ tags, const int* __restrict__ w2w,
    const int* __restrict__ ic, const int* __restrict__ dist,
    double* __restrict__ goldslots, double* __restrict__ logzslots,
    unsigned* __restrict__ donecnt, float* __restrict__ out)
{
    const int tid = threadIdx.x;
    const int wv  = tid >> 6;        // 0..7
    const int mh  = wv >> 2;         // m-half: holds m in {2mh, 2mh+1}
    const int wvc = wv & 3;          // column range 32wvc..
    const int ln  = tid & 63;
    const int lr  = ln & 15;         // A-row / B-col lane id
    const int hq  = ln >> 4;         // 0..3: k-slab and C/D row-quad
    const int grp = blockIdx.x;      // group id 0..255

    __shared__ float SS[32][130];                                // 16.6 KB stage tile
    __shared__ __align__(16) unsigned short A[2][GROUPC * KDIM]; // 8 KB dbuf, swizzled
    __shared__ double bg[8];
    __shared__ double bzred;
    __shared__ double redd[256];
    __shared__ int islast;

    // ---- stage E: 16 passes (m,ks); coalesced loads + LDS transpose ----
    // 512 threads: each loads 8 floats/pass; wave extracts only its 2 m's.
    s8v Bf[2][2][4];
    const int ncol = (wvc << 5) + lr;
    {
        const int sr = tid >> 4;              // LDS row 0..31
        const int sc = (tid & 15) << 3;       // LDS col 0..120
        float4 nx0, nx1;
        {
            const float* s = trans + (tid << 3);
            nx0 = *(const float4*)(s); nx1 = *(const float4*)(s + 4);
        }
        #pragma unroll
        for (int p = 0; p < 16; ++p) {        // p = m*4 + ks; src off = p<<12
            ((float2*)&SS[sr][sc])[0] = make_float2(nx0.x, nx0.y);
            ((float2*)&SS[sr][sc])[1] = make_float2(nx0.z, nx0.w);
            ((float2*)&SS[sr][sc + 4])[0] = make_float2(nx1.x, nx1.y);
            ((float2*)&SS[sr][sc + 4])[1] = make_float2(nx1.z, nx1.w);
            __syncthreads();
            if (p < 15) {                     // prefetch next pass under reads
                const float* s = trans + ((p + 1) << 12) + (tid << 3);
                nx0 = *(const float4*)(s); nx1 = *(const float4*)(s + 4);
            }
            if ((p >> 3) == mh) {             // my half only
                const int mloc = (p >> 2) & 1, ks = p & 3;
                s8v f0, f1;
                #pragma unroll
                for (int j = 0; j < 8; ++j) {
                    f0[j] = (short)bf16rne(__expf(SS[(hq << 3) + j][ncol]));
                    f1[j] = (short)bf16rne(__expf(SS[(hq << 3) + j][ncol + 16]));
                }
                Bf[mloc][0][ks] = f0;
                Bf[mloc][1][ks] = f1;
            }
            __syncthreads();
        }
    }

    // ---- gold: block covers 512 t's, 1 per thread ----
    {
        float gp = 0.f;
        const int t = 1 + (grp << 9) + tid;
        if (t < T_LEN) {
            const int tg  = tags[t];
            const int tgp = tags[t - 1];
            const int mm  = trans_idx(w2w[t - 1], ic[t - 1], dist[t - 1]);
            gp = cw[tg] * (trans[((size_t)mm * KDIM + tgp) * KDIM + tg] +
                           em[(size_t)t * KDIM + tg]);
        }
        if (grp == 0 && tid == 0) {
            const int tg0 = tags[0];
            gp += cw[tg0] * (start[tg0] + em[tg0]);
        }
        float r = gp;
        #pragma unroll
        for (int off = 32; off; off >>= 1) r += __shfl_down(r, off, 64);
        if (ln == 0) bg[wv] = (double)r;
    }

    // ---- init A tile (wave 0): row lr, k-slab hq*32..+31 ----
    if (wv == 0) {
        const int c_row = (grp << 4) + lr;
        #pragma unroll
        for (int kk = 0; kk < 32; kk += 2) {
            const int k = (hq << 5) + kk;
            float a0, a1;
            if (c_row == 0) {
                a0 = __expf(start[k] + em[k]);
                a1 = __expf(start[k + 1] + em[k + 1]);
            } else { a0 = 1.f; a1 = 1.f; }
            const int off = (lr << 8) + ((k << 1) ^ ((lr & 7) << 4));
            *(unsigned*)((char*)A[0] + off) =
                (unsigned)bf16rne(a0) | ((unsigned)bf16rne(a1) << 16);
        }
    }
    __syncthreads();

    // ---- per-row bookkeeping ----
    int t0r[4];
    #pragma unroll
    for (int r = 0; r < 4; ++r) {
        const int c_r = (grp << 4) + (hq << 2) + r;
        t0r[r] = (c_r == 0) ? 1 : (1 + c_r * CHUNK - WARM);
    }
    const int c_lr   = (grp << 4) + lr;     // row this lane tracks s/g for
    const int town_l = 1 + c_lr * CHUNK;
    const int tend_l = min(town_l + CHUNK, T_LEN);
    const int t0_l   = (c_lr == 0) ? 1 : (town_l - WARM);

    int pmw, pmi, pmd;
    {
        const int ix = min(t0_l - 1, T_LEN - 2);
        pmw = w2w[ix]; pmi = ic[ix]; pmd = dist[ix];
    }
    float pem[2][4];
    #pragma unroll
    for (int r = 0; r < 4; ++r) {
        const int t = min(t0r[r], T_LEN - 1);
        pem[0][r] = em[(size_t)t * KDIM + ncol];
        pem[1][r] = em[(size_t)t * KDIM + ncol + 16];
    }

    float g = 0.f;
    float sc4[4] = {1.f, 1.f, 1.f, 1.f};

    for (int it = 0; it <= NSTEP; ++it) {
        // (1) read A fragments (v after step t-1), swizzled
        s8v Af[4];
        #pragma unroll
        for (int ks = 0; ks < 4; ++ks) {
            const int off = (lr << 8) + (((ks << 6) + (hq << 4)) ^ ((lr & 7) << 4));
            Af[ks] = *(const s8v*)((const char*)A[it & 1] + off);
        }

        // (2) renorm bookkeeping on v(t-1): same events as rounds 3-6
        const bool trig = ((it & 7) == 0) || (grp == NGRP - 1 && it == NSTEP - 1);
        if (trig) {
            float s = 0.f;
            #pragma unroll
            for (int ks = 0; ks < 4; ++ks) {
                #pragma unroll
                for (int j = 0; j < 8; ++j)
                    s += bf16tof((unsigned short)Af[ks][j]);
            }
            s += __shfl_xor(s, 16, 64);
            s += __shfl_xor(s, 32, 64);       // full row-sum for row lr
            const int tprev = t0_l + it - 1;
            const bool dn = ((tprev & 7) == 0) || (tprev == T_LEN - 1);
            const float scl = dn ? (1.f / s) : 1.f;
            if (it == 0) {
                if (c_lr == 0) g += __logf(s);        // base measure log s0
            } else if (dn && tprev >= town_l && tprev < tend_l) {
                g += __logf(s);
            }
            #pragma unroll
            for (int r = 0; r < 4; ++r) sc4[r] = __shfl(scl, (hq << 2) + r, 64);
        }
        if (it == NSTEP) break;

        // (3) per-row transition index + emission factors
        const int mcur = trans_idx(pmw, pmi, pmd);
        int m4[4];
        #pragma unroll
        for (int r = 0; r < 4; ++r) m4[r] = __shfl(mcur, (hq << 2) + r, 64);
        float dv[2][4];
        #pragma unroll
        for (int nt = 0; nt < 2; ++nt) {
            #pragma unroll
            for (int r = 0; r < 4; ++r)
                dv[nt][r] = __expf(pem[nt][r] - CSHIFT) * sc4[r];
        }

        // (4) prefetch next step (issued before MFMA so latency hides)
        {
            const int ix = min(t0_l + it, T_LEN - 2);
            pmw = w2w[ix]; pmi = ic[ix]; pmd = dist[ix];
        }
        #pragma unroll
        for (int r = 0; r < 4; ++r) {
            const int t = min(t0r[r] + it + 1, T_LEN - 1);
            pem[0][r] = em[(size_t)t * KDIM + ncol];
            pem[1][r] = em[(size_t)t * KDIM + ncol + 16];
        }

        // (5) 16 MFMAs: my 2 m's, 2 N-tiles, K=128
        v4f acc[2][2];
        #pragma unroll
        for (int m = 0; m < 2; ++m) {
            #pragma unroll
            for (int nt = 0; nt < 2; ++nt) acc[m][nt] = (v4f)0.f;
        }
        #pragma unroll
        for (int ks = 0; ks < 4; ++ks) {
            #pragma unroll
            for (int m = 0; m < 2; ++m) {
                #pragma unroll
                for (int nt = 0; nt < 2; ++nt)
                    acc[m][nt] = __builtin_amdgcn_mfma_f32_16x16x32_bf16(
                        Af[ks], Bf[m][nt][ks], acc[m][nt], 0, 0, 0);
            }
        }

        // (6) rows whose m is in my half: select, scale, write next A tile
        #pragma unroll
        for (int nt = 0; nt < 2; ++nt) {
            #pragma unroll
            for (int r = 0; r < 4; ++r) {
                const int mm = m4[r];
                if ((mm >> 1) == mh) {
                    const float y = ((mm & 1) ? acc[1][nt][r] : acc[0][nt][r])
                                    * dv[nt][r];
                    const int row = (hq << 2) + r;
                    const int col = (wvc << 5) + (nt << 4) + lr;
                    const int off = (row << 8) + ((col << 1) ^ ((row & 7) << 4));
                    *(unsigned short*)((char*)A[(it & 1) ^ 1] + off) = bf16rne(y);
                }
            }
        }
        #pragma unroll
        for (int r = 0; r < 4; ++r) sc4[r] = 1.f;
        __syncthreads();
    }

    // ---- logZ reduce: lanes<16 of wave 0 hold g for rows 0..15 ----
    if (wv == 0) {
        float gz = (ln < 16) ? (g + CSHIFT * (float)(tend_l - town_l)) : 0.f;
        float r = gz;
        #pragma unroll
        for (int off = 32; off; off >>= 1) r += __shfl_down(r, off, 64);
        if (ln == 0) bzred = (double)r;
    }
    __syncthreads();

    // ---- publish slots; last block reduces everything ----
    if (tid == 0) {
        goldslots[grp] = bg[0] + bg[1] + bg[2] + bg[3] +
                         bg[4] + bg[5] + bg[6] + bg[7];
        logzslots[grp] = bzred;
        __threadfence();
        const unsigned prev = atomicAdd(donecnt, 1u);
        islast = (prev == NGRP - 1) ? 1 : 0;
    }
    __syncthreads();
    if (islast) {
        __threadfence();
        if (tid < 256) redd[tid] = goldslots[tid];
        __syncthreads();
        for (int s = 128; s > 0; s >>= 1) {
            if (tid < s && tid < 256) redd[tid] += redd[tid + s];
            __syncthreads();
        }
        if (tid == 0) out[0] = (float)redd[0];
        __syncthreads();
        if (tid < 256) redd[tid] = logzslots[tid];
        __syncthreads();
        for (int s = 128; s > 0; s >>= 1) {
            if (tid < s && tid < 256) redd[tid] += redd[tid + s];
            __syncthreads();
        }
        if (tid == 0) out[1] = (float)redd[0];
    }
}

extern "C" void kernel_launch(void* const* d_in, const int* in_sizes, int n_in,
                              void* d_out, int out_size, void* d_ws, size_t ws_size,
                              hipStream_t stream) {
    const float* emissions = (const float*)d_in[0];
    const float* trans     = (const float*)d_in[1];
    const float* start     = (const float*)d_in[2];
    const float* cw        = (const float*)d_in[3];
    const int*   tags      = (const int*)d_in[4];
    const int*   w2w       = (const int*)d_in[5];
    const int*   icnt      = (const int*)d_in[6];
    const int*   dist      = (const int*)d_in[7];

    double*   goldslots = (double*)d_ws;            // NGRP doubles (256)
    double*   logzslots = (double*)d_ws + 256;      // NGRP doubles (256)
    unsigned* donecnt   = (unsigned*)((double*)d_ws + 512);

    hipMemsetAsync(donecnt, 0, sizeof(unsigned), stream);
    scan_kernel<<<NGRP, 512, 0, stream>>>(emissions, trans, start, cw, tags,
                                          w2w, icnt, dist, goldslots, logzslots,
                                          donecnt, (float*)d_out);
}